// Round 1
// baseline (81.080 us; speedup 1.0000x reference)
//
#include <hip/hip_runtime.h>

#ifndef __has_builtin
#define __has_builtin(x) 0
#endif

__device__ __forceinline__ float fast_rsqrt(float x) {
#if __has_builtin(__builtin_amdgcn_rsqf)
    return __builtin_amdgcn_rsqf(x);     // raw v_rsq_f32, ~1 ulp — plenty for 7.9e-5 abs tol
#else
    return rsqrtf(x);
#endif
}

__device__ __forceinline__ float fast_rcp(float x) {
#if __has_builtin(__builtin_amdgcn_rcpf)
    return __builtin_amdgcn_rcpf(x);
#else
    return 1.0f / x;
#endif
}

constexpr int Bc = 2048;   // batch
constexpr int Fc = 256;    // in_features
constexpr int Cc = 256;    // clusters (== Fc)
constexpr int G  = 4;      // batch rows per block -> 512 blocks, 2 blocks/CU

// out[b,i] = num[b,i] / den[b]
//   num[b,i] = sum_j rsqrt(1 + (x[b,j] - mu[j,i])^2)   (sqrt(2) factor cancels)
//   den[b]   = sum_i num[b,i]
__global__ __launch_bounds__(256)
void clusteringLayer_77154792506116_kernel(const float* __restrict__ x,
                                           const float* __restrict__ mu,
                                           float* __restrict__ out) {
    const int i  = threadIdx.x;           // cluster index 0..255
    const int b0 = blockIdx.x * G;

    __shared__ float xs[G][Fc];           // 4 KB: the G batch rows of x
    __shared__ float wsum[4][G];          // per-wave partial sums (4 waves/block)

    #pragma unroll
    for (int g = 0; g < G; ++g)
        xs[g][i] = x[(size_t)(b0 + g) * Fc + i];   // coalesced
    __syncthreads();

    float acc[G] = {0.f, 0.f, 0.f, 0.f};

    #pragma unroll 4
    for (int j = 0; j < Fc; ++j) {
        const float m = mu[(size_t)j * Fc + i];    // coalesced, L2-resident
        #pragma unroll
        for (int g = 0; g < G; ++g) {
            const float d = xs[g][j] - m;          // xs[g][j]: LDS broadcast (uniform)
            acc[g] += fast_rsqrt(fmaf(d, d, 1.0f));
        }
    }

    // Block-wide reduction of acc[g] over the 256 i's -> den per batch row.
    const int lane = i & 63;
    const int wv   = i >> 6;
    #pragma unroll
    for (int g = 0; g < G; ++g) {
        float v = acc[g];
        #pragma unroll
        for (int off = 1; off < 64; off <<= 1)
            v += __shfl_xor(v, off, 64);
        if (lane == 0) wsum[wv][g] = v;
    }
    __syncthreads();

    #pragma unroll
    for (int g = 0; g < G; ++g) {
        const float den = wsum[0][g] + wsum[1][g] + wsum[2][g] + wsum[3][g];
        out[(size_t)(b0 + g) * Cc + i] = acc[g] * fast_rcp(den);
    }
}

extern "C" void kernel_launch(void* const* d_in, const int* in_sizes, int n_in,
                              void* d_out, int out_size, void* d_ws, size_t ws_size,
                              hipStream_t stream) {
    const float* x  = (const float*)d_in[0];   // (2048, 256) f32
    const float* mu = (const float*)d_in[1];   // (256, 256)  f32
    float* out = (float*)d_out;                // (2048, 256) f32

    dim3 grid(Bc / G), block(Fc);
    hipLaunchKernelGGL(clusteringLayer_77154792506116_kernel, grid, block, 0, stream,
                       x, mu, out);
}

// Round 2
// 77.584 us; speedup vs baseline: 1.0451x; 1.0451x over previous
//
#include <hip/hip_runtime.h>

#ifndef __has_builtin
#define __has_builtin(x) 0
#endif

__device__ __forceinline__ float fast_rsqrt(float x) {
#if __has_builtin(__builtin_amdgcn_rsqf)
    return __builtin_amdgcn_rsqf(x);     // raw v_rsq_f32
#else
    return rsqrtf(x);
#endif
}

__device__ __forceinline__ float fast_rcp(float x) {
#if __has_builtin(__builtin_amdgcn_rcpf)
    return __builtin_amdgcn_rcpf(x);
#else
    return 1.0f / x;
#endif
}

constexpr int Bc = 2048;   // batch
constexpr int Fc = 256;    // in_features
constexpr int Cc = 256;    // clusters

// out[b,i] = num[b,i] / den[b]
//   num[b,i] = sum_j rsqrt(1 + (x[b,j] - mu[j,i])^2)   (sqrt(2) factor cancels in num/den)
//   den[b]   = sum_i num[b,i]
//
// Layout: 4 waves/block; wave w owns batch row b = blockIdx*4 + w.
// Lane t owns clusters 4t..4t+3 (contiguous -> dwordx4 mu loads).
// x[b,j] is block/wave-uniform -> scalar loads (SMEM path), no LDS at all.
__global__ __launch_bounds__(256)
void clusteringLayer_77154792506116_kernel(const float* __restrict__ x,
                                           const float* __restrict__ mu,
                                           float* __restrict__ out) {
    const int wv   = threadIdx.x >> 6;
    const int lane = threadIdx.x & 63;
    const int b    = blockIdx.x * 4 + wv;

    const float*  xr  = x + (size_t)b * Fc;                  // uniform base
    const float4* mu4 = (const float4*)mu + lane;            // mu[j][4*lane..4*lane+3]

    float a0 = 0.f, a1 = 0.f, a2 = 0.f, a3 = 0.f;

    #pragma unroll 8
    for (int j = 0; j < Fc; ++j) {
        const float4 m  = mu4[j * (Cc / 4)];                 // global_load_dwordx4, coalesced
        const float  xv = xr[j];                             // uniform -> s_load
        const float d0 = xv - m.x;
        const float d1 = xv - m.y;
        const float d2 = xv - m.z;
        const float d3 = xv - m.w;
        a0 += fast_rsqrt(fmaf(d0, d0, 1.0f));
        a1 += fast_rsqrt(fmaf(d1, d1, 1.0f));
        a2 += fast_rsqrt(fmaf(d2, d2, 1.0f));
        a3 += fast_rsqrt(fmaf(d3, d3, 1.0f));
    }

    // den[b]: reduce (a0+a1+a2+a3) across the 64 lanes (butterfly, stays in-wave)
    float s = (a0 + a1) + (a2 + a3);
    #pragma unroll
    for (int off = 1; off < 64; off <<= 1)
        s += __shfl_xor(s, off, 64);

    const float r = fast_rcp(s);
    float4 o;
    o.x = a0 * r; o.y = a1 * r; o.z = a2 * r; o.w = a3 * r;
    ((float4*)(out + (size_t)b * Cc))[lane] = o;             // coalesced dwordx4 store
}

extern "C" void kernel_launch(void* const* d_in, const int* in_sizes, int n_in,
                              void* d_out, int out_size, void* d_ws, size_t ws_size,
                              hipStream_t stream) {
    const float* x  = (const float*)d_in[0];   // (2048, 256) f32
    const float* mu = (const float*)d_in[1];   // (256, 256)  f32
    float* out = (float*)d_out;                // (2048, 256) f32

    dim3 grid(Bc / 4), block(256);             // 512 blocks x 4 waves = 2048 waves
    hipLaunchKernelGGL(clusteringLayer_77154792506116_kernel, grid, block, 0, stream,
                       x, mu, out);
}

// Round 3
// 73.970 us; speedup vs baseline: 1.0961x; 1.0489x over previous
//
#include <hip/hip_runtime.h>

#ifndef __has_builtin
#define __has_builtin(x) 0
#endif

__device__ __forceinline__ float fast_rsqrt(float x) {
#if __has_builtin(__builtin_amdgcn_rsqf)
    return __builtin_amdgcn_rsqf(x);     // raw v_rsq_f32
#else
    return rsqrtf(x);
#endif
}

__device__ __forceinline__ float fast_rcp(float x) {
#if __has_builtin(__builtin_amdgcn_rcpf)
    return __builtin_amdgcn_rcpf(x);
#else
    return 1.0f / x;
#endif
}

constexpr int Bc = 2048;   // batch
constexpr int Fc = 256;    // in_features
constexpr int Cc = 256;    // clusters
constexpr int RB = 4;      // batch rows per block
constexpr int NW = 8;      // waves per block (512 threads)
constexpr int JW = Fc / NW; // 32: j-slice per wave

// out[b,i] = num[b,i]/den[b];  num = sum_j rsqrt(1+(x[b,j]-mu[j,i])^2)  (sqrt2 cancels)
//
// Block(512 thr, 8 waves) owns 4 batch rows. Wave w covers j in [w*32, w*32+32),
// all 256 clusters (4 per lane, dwordx4), all 4 rows -> 16 elems per mu load.
// mu L2 traffic /4 vs one-row-per-wave; 4096 waves -> 4 waves/SIMD.
// x is block-uniform + wave-uniform j -> scalar s_load path.
// Partial sums over the 8 j-slices reduced through LDS.
__global__ __launch_bounds__(512, 4)
void clusteringLayer_77154792506116_kernel(const float* __restrict__ x,
                                           const float* __restrict__ mu,
                                           float* __restrict__ out) {
    const int tid  = threadIdx.x;
    const int wv   = tid >> 6;
    const int lane = tid & 63;
    const int b0   = blockIdx.x * RB;

    __shared__ float red[NW][RB][Cc];   // 32 KB partial nums
    __shared__ float denp[NW];          // per-wave den partials

    const int    j0  = __builtin_amdgcn_readfirstlane(wv * JW);  // SGPR
    const float* xp  = x + (size_t)b0 * Fc;                      // scalar base
    const float4* mu4 = (const float4*)mu + lane;                // mu[j][4l..4l+3]

    float4 acc[RB];
    #pragma unroll
    for (int r = 0; r < RB; ++r) acc[r] = make_float4(0.f, 0.f, 0.f, 0.f);

    #pragma unroll 4
    for (int jj = 0; jj < JW; ++jj) {
        const int    j = j0 + jj;
        const float4 m = mu4[(size_t)j * (Cc / 4)];   // global_load_dwordx4 (L2-resident)
        #pragma unroll
        for (int r = 0; r < RB; ++r) {
            const float xv = xp[r * Fc + j];          // fully scalar -> s_load
            const float d0 = xv - m.x;
            const float d1 = xv - m.y;
            const float d2 = xv - m.z;
            const float d3 = xv - m.w;
            acc[r].x += fast_rsqrt(fmaf(d0, d0, 1.0f));
            acc[r].y += fast_rsqrt(fmaf(d1, d1, 1.0f));
            acc[r].z += fast_rsqrt(fmaf(d2, d2, 1.0f));
            acc[r].w += fast_rsqrt(fmaf(d3, d3, 1.0f));
        }
    }

    // stage per-wave partials (contiguous b128 writes: conflict-free)
    #pragma unroll
    for (int r = 0; r < RB; ++r)
        *(float4*)&red[wv][r][lane * 4] = acc[r];
    __syncthreads();

    // each thread reduces 2 output elements across the 8 j-slice partials
    const int e = tid * 2;                        // flat [RB][Cc] index, 0..1022
    float2 s = make_float2(0.f, 0.f);
    #pragma unroll
    for (int w = 0; w < NW; ++w) {
        const float2 v = *(const float2*)&(((const float*)red[w])[e]);
        s.x += v.x; s.y += v.y;
    }

    // den per row: each wave's e-range sits inside one row (row = tid>>7 = wv>>1)
    float p = s.x + s.y;
    #pragma unroll
    for (int off = 1; off < 64; off <<= 1)
        p += __shfl_xor(p, off, 64);
    if (lane == 0) denp[wv] = p;
    __syncthreads();

    const int   r   = tid >> 7;                   // row of this thread's elements
    const float den = denp[2 * r] + denp[2 * r + 1];
    const float rc  = fast_rcp(den);

    float2 o = make_float2(s.x * rc, s.y * rc);
    *(float2*)&out[(size_t)b0 * Cc + e] = o;      // coalesced float2 store
}

extern "C" void kernel_launch(void* const* d_in, const int* in_sizes, int n_in,
                              void* d_out, int out_size, void* d_ws, size_t ws_size,
                              hipStream_t stream) {
    const float* x  = (const float*)d_in[0];   // (2048, 256) f32
    const float* mu = (const float*)d_in[1];   // (256, 256)  f32
    float* out = (float*)d_out;                // (2048, 256) f32

    dim3 grid(Bc / RB), block(NW * 64);        // 512 blocks x 8 waves = 4096 waves
    hipLaunchKernelGGL(clusteringLayer_77154792506116_kernel, grid, block, 0, stream,
                       x, mu, out);
}